// Round 7
// baseline (207.740 us; speedup 1.0000x reference)
//
#include <hip/hip_runtime.h>
#include <hip/hip_bf16.h>

#define HID 256
#define NROWS 2048
#define NITER 8
#define GRID (NROWS / NITER)   // 256 blocks = 1 per CU, persistent
#define PITCH 264              // bf16 row pitch: 256 + 8 pad (16B-aligned rows)

typedef __attribute__((ext_vector_type(8))) short short8;   // 8 bf16 (MFMA A/B frag)
typedef __attribute__((ext_vector_type(4))) float float4v;
typedef __attribute__((ext_vector_type(4))) unsigned short ushort4v;

__device__ __forceinline__ float bf2f(unsigned short u) {
    return __uint_as_float(((unsigned int)u) << 16);
}

__device__ __forceinline__ unsigned int pk_bf16(float a, float b) {
    __hip_bfloat162 p = __float22bfloat162_rn(float2{a, b});  // v_cvt_pk_bf16_f32
    return *(unsigned int*)&p;
}

__device__ __forceinline__ float tanh_fast(float x) {
    float e = __builtin_amdgcn_exp2f(x * 2.8853900817779268f); // exp(2x)
    return 1.0f - 2.0f * __builtin_amdgcn_rcpf(e + 1.0f);
}

// exp(s) for |s| <= 1/16 (|ctx|<=1/16 bounds the score): 3-FMA Taylor, err ~6e-7
__device__ __forceinline__ float exp_small(float s) {
    float p = __builtin_fmaf(s, 0.16666667f, 0.5f);
    p = __builtin_fmaf(p, s, 1.0f);
    return __builtin_fmaf(p, s, 1.0f);
}

// Workgroup barrier that waits ONLY on LDS (lgkmcnt(0)); in-flight global
// prefetch loads (vmcnt) sail through. 0xC07F = vmcnt=63, expcnt=7, lgkmcnt=0.
__device__ __forceinline__ void barrier_lds_only() {
    __asm__ volatile("" ::: "memory");
    __builtin_amdgcn_s_waitcnt(0xC07F);
    __builtin_amdgcn_s_barrier();
    __asm__ volatile("" ::: "memory");
}

// sum across each 16-lane DPP row (VALU pipe, no LDS)
__device__ __forceinline__ float row16_sum(float v) {
    float t;
    t = __builtin_bit_cast(float, __builtin_amdgcn_update_dpp(
            0, __builtin_bit_cast(int, v), 0xB1, 0xf, 0xf, true));  // quad_perm(1,0,3,2)
    v += t;
    t = __builtin_bit_cast(float, __builtin_amdgcn_update_dpp(
            0, __builtin_bit_cast(int, v), 0x4E, 0xf, 0xf, true));  // quad_perm(2,3,0,1)
    v += t;
    t = __builtin_bit_cast(float, __builtin_amdgcn_update_dpp(
            0, __builtin_bit_cast(int, v), 0x124, 0xf, 0xf, true)); // row_ror:4
    v += t;
    t = __builtin_bit_cast(float, __builtin_amdgcn_update_dpp(
            0, __builtin_bit_cast(int, v), 0x128, 0xf, 0xf, true)); // row_ror:8
    v += t;
    return v;
}

// W (256x256 f32) -> bf16 in workspace (ws re-poisoned every launch, so redo)
__global__ void cvt_w(const float* __restrict__ W, unsigned short* __restrict__ Wb) {
    int i = blockIdx.x * 256 + threadIdx.x;
    float4v v = ((const float4v*)W)[i];
    unsigned int lo = pk_bf16(v.x, v.y), hi = pk_bf16(v.z, v.w);
    ushort4v u;
    u.x = (unsigned short)lo; u.y = (unsigned short)(lo >> 16);
    u.z = (unsigned short)hi; u.w = (unsigned short)(hi >> 16);
    ((ushort4v*)Wb)[i] = u;
}

// Persistent, software-pipelined: per iter t -> issue reg-loads for t+1;
// compute on xs[t&1] (LDS barriers are lgkm-only, loads stay in flight);
// cvt vbuf -> xs[(t+1)&1]; one full __syncthreads per iter.
__global__ __launch_bounds__(512, 2) void attend_fused(
    const float* __restrict__ x, const unsigned short* __restrict__ Wb,
    const float* __restrict__ bias, const float* __restrict__ ctx,
    float* __restrict__ out)
{
    __shared__ unsigned short xs[2][64 * PITCH];  // double-buffered bf16 tile (~66 KB)
    __shared__ float wsum[8][64];
    __shared__ float rinv[64];

    const int tid  = threadIdx.x;
    const int wave = tid >> 6;    // 0..7
    const int lane = tid & 63;
    const int q    = lane >> 4;   // quad 0..3
    const int c    = lane & 15;
    const int obase = wave * 32;  // wave's 32 output cols; lane's pair: obase+2c+{0,1}

    // ---- loop-invariant: epilogue constants + ALL B fragments in registers ----
    float bb[2], cc[2];
#pragma unroll
    for (int nt = 0; nt < 2; ++nt) {
        bb[nt] = bias[obase + 2 * c + nt];
        cc[nt] = ctx[obase + 2 * c + nt];
    }
    short8 bfrag[8][2];           // 64 VGPRs: whole B tile for this wave
#pragma unroll
    for (int nt = 0; nt < 2; ++nt) {
        const unsigned short* wr = &Wb[(size_t)(obase + 2 * c + nt) * 256 + q * 8];
#pragma unroll
        for (int kt = 0; kt < 8; ++kt)
            bfrag[kt][nt] = *(const short8*)(wr + kt * 32);
    }

    const int n0 = blockIdx.x * NITER;

    // ---- prologue: load + cvt tile n0 into xs[0] ----
    {
        const float4v* xg = (const float4v*)(x + (size_t)n0 * (64 * 256));
        float4v v0[8];
#pragma unroll
        for (int i = 0; i < 8; ++i)
            v0[i] = xg[tid + 512 * i];
#pragma unroll
        for (int i = 0; i < 8; ++i) {
            const int chunk = tid + 512 * i;
            const int r = chunk >> 6, col4 = (chunk & 63) * 4;
            uint2 u;
            u.x = pk_bf16(v0[i].x, v0[i].y);
            u.y = pk_bf16(v0[i].z, v0[i].w);
            *(uint2*)&xs[0][r * PITCH + col4] = u;
        }
    }
    __syncthreads();

    for (int it = 0; it < NITER; ++it) {
        const int n = n0 + it;
        const int cur = it & 1;

        // ---- issue next tile's loads NOW; they fly under the whole compute ----
        float4v vbuf[8];
        if (it + 1 < NITER) {
            const float4v* xg = (const float4v*)(x + (size_t)(n + 1) * (64 * 256));
#pragma unroll
            for (int i = 0; i < 8; ++i)
                vbuf[i] = xg[tid + 512 * i];
        }

        // ---- GEMM: acc[mt][nt] over 64 rows x 32 cols; zero vmem in loop ----
        float4v acc[4][2];
#pragma unroll
        for (int mt = 0; mt < 4; ++mt)
#pragma unroll
            for (int nt = 0; nt < 2; ++nt)
                acc[mt][nt] = (float4v){0.f, 0.f, 0.f, 0.f};

#pragma unroll
        for (int kt = 0; kt < 8; ++kt) {
            short8 a[4];
#pragma unroll
            for (int mt = 0; mt < 4; ++mt)
                a[mt] = *(const short8*)&xs[cur][(mt * 16 + c) * PITCH + kt * 32 + q * 8];
#pragma unroll
            for (int nt = 0; nt < 2; ++nt)
#pragma unroll
                for (int mt = 0; mt < 4; ++mt)
                    acc[mt][nt] = __builtin_amdgcn_mfma_f32_16x16x32_bf16(
                        a[mt], bfrag[kt][nt], acc[mt][nt], 0, 0, 0);
        }

        // ---- epilogue: e = exp(tanh(acc+b)*ctx); row sums via DPP ----
        // D layout: row = 16*mt + 4*q + reg, col = obase + 2*c + nt
        float psum[4][4];
#pragma unroll
        for (int mt = 0; mt < 4; ++mt)
#pragma unroll
            for (int r = 0; r < 4; ++r)
                psum[mt][r] = 0.f;

#pragma unroll
        for (int nt = 0; nt < 2; ++nt) {
#pragma unroll
            for (int mt = 0; mt < 4; ++mt) {
#pragma unroll
                for (int r = 0; r < 4; ++r) {
                    float s = tanh_fast(acc[mt][nt][r] + bb[nt]) * cc[nt];
                    float e = exp_small(s);
                    acc[mt][nt][r] = e;
                    psum[mt][r] += e;
                }
            }
        }
#pragma unroll
        for (int mt = 0; mt < 4; ++mt)
#pragma unroll
            for (int r = 0; r < 4; ++r)
                psum[mt][r] = row16_sum(psum[mt][r]);
        if (c == 0) {
#pragma unroll
            for (int mt = 0; mt < 4; ++mt)
#pragma unroll
                for (int r = 0; r < 4; ++r)
                    wsum[wave][mt * 16 + q * 4 + r] = psum[mt][r];
        }
        barrier_lds_only();   // prefetch loads stay in flight
        if (tid < 64) {
            float t = wsum[0][tid] + wsum[1][tid] + wsum[2][tid] + wsum[3][tid]
                    + wsum[4][tid] + wsum[5][tid] + wsum[6][tid] + wsum[7][tid];
            rinv[tid] = __builtin_amdgcn_rcpf(t);
        }
        barrier_lds_only();   // prefetch loads stay in flight

        // ---- out[h] = sum_w x[w][h] * e[w][h] * rinv[w]; paired-col b32 reads ----
        float ri[4][4];
#pragma unroll
        for (int mt = 0; mt < 4; ++mt)
#pragma unroll
            for (int r = 0; r < 4; ++r)
                ri[mt][r] = rinv[mt * 16 + q * 4 + r];

        float outp[2] = {0.f, 0.f};
#pragma unroll
        for (int mt = 0; mt < 4; ++mt) {
#pragma unroll
            for (int r = 0; r < 4; ++r) {
                const int w = mt * 16 + q * 4 + r;
                unsigned int pair = *(const unsigned int*)&xs[cur][w * PITCH + obase + 2 * c];
                const float wgt = ri[mt][r];
                outp[0] += bf2f((unsigned short)pair)         * (acc[mt][0][r] * wgt);
                outp[1] += bf2f((unsigned short)(pair >> 16)) * (acc[mt][1][r] * wgt);
            }
        }
#pragma unroll
        for (int nt = 0; nt < 2; ++nt) {
            float v = outp[nt];
            v += __shfl_xor(v, 16);   // combine the 4 quads' disjoint w-ranges
            v += __shfl_xor(v, 32);
            outp[nt] = v;
        }
        if (q == 0)
            *(float2*)&out[(size_t)n * HID + obase + 2 * c] = float2{outp[0], outp[1]};

        // ---- cvt prefetched registers -> other xs buffer (waits vmcnt here) ----
        if (it + 1 < NITER) {
#pragma unroll
            for (int i = 0; i < 8; ++i) {
                const int chunk = tid + 512 * i;
                const int r = chunk >> 6, col4 = (chunk & 63) * 4;
                uint2 u;
                u.x = pk_bf16(vbuf[i].x, vbuf[i].y);
                u.y = pk_bf16(vbuf[i].z, vbuf[i].w);
                *(uint2*)&xs[cur ^ 1][r * PITCH + col4] = u;
            }
            __syncthreads();   // the one full (vmcnt-draining) barrier per iter
        }
    }
}

extern "C" void kernel_launch(void* const* d_in, const int* in_sizes, int n_in,
                              void* d_out, int out_size, void* d_ws, size_t ws_size,
                              hipStream_t stream) {
    const float* x    = (const float*)d_in[0];   // [2048, 64, 256]
    const float* W    = (const float*)d_in[1];   // [256, 256]
    const float* bias = (const float*)d_in[2];   // [256]
    const float* ctx  = (const float*)d_in[3];   // [256]
    unsigned short* Wb = (unsigned short*)d_ws;  // 128 KB bf16 W

    cvt_w<<<64, 256, 0, stream>>>(W, Wb);
    attend_fused<<<GRID, 512, 0, stream>>>(x, Wb, bias, ctx, (float*)d_out);
}